// Round 1
// baseline (901.874 us; speedup 1.0000x reference)
//
#include <hip/hip_runtime.h>
#include <hip/hip_bf16.h>

// Problem geometry
#define N_ROWS 32000   // Q_OUT*Q_IN*NUM_P
#define SB     12      // SCALAR_BASIS
#define FC     720     // FILTER_C
#define FD     2704    // FILTER_DIM
#define KP     2720    // FD padded to multiple of BK (=32): 85*32
#define OCOLS  2704    // DIM_OUT*DIM_IN
#define OPAD   2816    // OCOLS padded to multiple of BN (=128): 22*128
#define ANGD   25

#define BM 128
#define BN 128
#define BK 32

typedef __attribute__((ext_vector_type(8))) short bf16x8;
typedef __attribute__((ext_vector_type(4))) float f32x4;

__device__ __forceinline__ void gload16(const void* g, void* l) {
    __builtin_amdgcn_global_load_lds(
        (const __attribute__((address_space(1))) void*)g,
        (__attribute__((address_space(3))) void*)l, 16, 0, 0);
}

// ---------------------------------------------------------------------------
// Kernel 1: per-row n, compute sc = sk @ (W/sqrt(12)) into LDS, then expand
// filt[n, off_l + c*m + j] = sc[s_l + c] * ang[a_l + j], write bf16 padded
// row of length KP (pad cols [2704,2720) = 0).
// ---------------------------------------------------------------------------
__global__ void build_filt(const float* __restrict__ sk,   // (N, 12)
                           const float* __restrict__ ang,  // (N, 25)
                           const float* __restrict__ W,    // (12, 720)
                           __hip_bfloat16* __restrict__ filt) // (N, KP)
{
    const int n   = blockIdx.x;
    const int tid = threadIdx.x;  // 256
    __shared__ float s_sc[FC];
    __shared__ float s_ang[ANGD];
    __shared__ float s_sk[SB];

    if (tid < SB)  s_sk[tid]       = sk[(size_t)n * SB + tid];
    if (tid >= 32 && tid < 32 + ANGD) s_ang[tid - 32] = ang[(size_t)n * ANGD + (tid - 32)];
    __syncthreads();

    const float inv = 0.28867513459481288f; // 1/sqrt(12)
    for (int c = tid; c < FC; c += 256) {
        float acc = 0.f;
        #pragma unroll
        for (int s = 0; s < SB; ++s) acc += s_sk[s] * W[s * FC + c];
        s_sc[c] = acc * inv;
    }
    __syncthreads();

    const size_t base = (size_t)n * KP;
    for (int f = tid; f < KP; f += 256) {
        float v = 0.f;
        if (f < FD) {
            int c, j, a;
            if (f < 144)       { c = f;                         j = 0;            a = 0;  }
            else if (f < 960)  { int t = f - 144;  c = 144 + t/3; j = t - (t/3)*3; a = 1;  }
            else if (f < 2000) { int t = f - 960;  c = 416 + t/5; j = t - (t/5)*5; a = 4;  }
            else if (f < 2560) { int t = f - 2000; c = 624 + t/7; j = t - (t/7)*7; a = 9;  }
            else               { int t = f - 2560; c = 704 + t/9; j = t - (t/9)*9; a = 16; }
            v = s_sc[c] * s_ang[a + j];
        }
        filt[base + f] = __float2bfloat16(v);
    }
}

// ---------------------------------------------------------------------------
// Kernel 2: TP_mixing (2704x2704 f32) -> bf16 padded (OPAD x KP), pad = 0
// ---------------------------------------------------------------------------
__global__ void cvt_M(const float* __restrict__ M, __hip_bfloat16* __restrict__ out)
{
    int idx = blockIdx.x * 256 + threadIdx.x;
    const int total = OPAD * KP;
    if (idx >= total) return;
    int o = idx / KP;
    int k = idx - o * KP;
    float v = (o < OCOLS && k < FD) ? M[(size_t)o * FD + k] : 0.f;
    out[idx] = __float2bfloat16(v);
}

// ---------------------------------------------------------------------------
// Kernel 3: C[n,o] = sum_f A[n,f] * B[o,f]   (A: N_ROWS x KP bf16,
// B: OPAD x KP bf16, C: N_ROWS x OCOLS f32).  m97 structure: 128x128 tile,
// 4 waves (2x2), each wave 64x64 via 4x4 frags of 16x16x32 MFMA,
// global_load_lds width-16 staging, 2 barriers per K-step.
// ---------------------------------------------------------------------------
__global__ __launch_bounds__(256) void gemm_bt(
    const __hip_bfloat16* __restrict__ A,
    const __hip_bfloat16* __restrict__ B,
    float* __restrict__ C)
{
    __shared__ __align__(16) __hip_bfloat16 As[BM * BK];
    __shared__ __align__(16) __hip_bfloat16 Bs[BN * BK];

    const int tid  = threadIdx.x;
    const int wave = tid >> 6;
    const int lane = tid & 63;
    const int bn = blockIdx.x;       // 22 tiles of columns (o)
    const int bm = blockIdx.y;       // 250 tiles of rows (n)
    const int row0 = bm * BM;
    const int col0 = bn * BN;

    // Staging: wave w stages chunks {2w, 2w+1} (1024 B each) of both tiles.
    // Chunk c covers rows 16c..16c+15 of the [128][32] bf16 row-major tile;
    // lane covers row 16c + lane/4, bf16 cols (lane&3)*8 .. +7 (16 B).
    const int srow = 32 * wave + (lane >> 2);
    const int scol = (lane & 3) * 8;
    const __hip_bfloat16* ga0 = A + (size_t)(row0 + srow) * KP + scol;
    const __hip_bfloat16* ga1 = ga0 + (size_t)16 * KP;
    const __hip_bfloat16* gb0 = B + (size_t)(col0 + srow) * KP + scol;
    const __hip_bfloat16* gb1 = gb0 + (size_t)16 * KP;
    __hip_bfloat16* la0 = As + 2 * wave * 512;   // 512 bf16 = 1024 B chunk
    __hip_bfloat16* la1 = la0 + 512;
    __hip_bfloat16* lb0 = Bs + 2 * wave * 512;
    __hip_bfloat16* lb1 = lb0 + 512;

    // Fragment read pointers (A: row = lane&15, k-octet = lane>>4)
    const int wr = wave >> 1, wc = wave & 1;
    const __hip_bfloat16* pa = As + (wr * 64 + (lane & 15)) * BK + ((lane >> 4) << 3);
    const __hip_bfloat16* pb = Bs + (wc * 64 + (lane & 15)) * BK + ((lane >> 4) << 3);

    f32x4 acc[4][4] = {};

    for (int kt = 0; kt < KP / BK; ++kt) {
        gload16(ga0, la0);
        gload16(ga1, la1);
        gload16(gb0, lb0);
        gload16(gb1, lb1);
        ga0 += BK; ga1 += BK; gb0 += BK; gb1 += BK;
        __syncthreads();   // compiler drains vmcnt(0) before s_barrier

        bf16x8 af[4], bfr[4];
        #pragma unroll
        for (int m = 0; m < 4; ++m) af[m]  = *(const bf16x8*)(pa + m * 16 * BK);
        #pragma unroll
        for (int n = 0; n < 4; ++n) bfr[n] = *(const bf16x8*)(pb + n * 16 * BK);
        #pragma unroll
        for (int m = 0; m < 4; ++m) {
            #pragma unroll
            for (int n = 0; n < 4; ++n) {
                acc[m][n] = __builtin_amdgcn_mfma_f32_16x16x32_bf16(
                    af[m], bfr[n], acc[m][n], 0, 0, 0);
            }
        }
        __syncthreads();   // all reads done before next stage overwrites
    }

    // Epilogue: C/D layout col = lane&15, row = (lane>>4)*4 + r  [m89-verified]
    const int orow = row0 + wr * 64 + ((lane >> 4) << 2);
    const int ocol = col0 + wc * 64 + (lane & 15);
    #pragma unroll
    for (int m = 0; m < 4; ++m) {
        #pragma unroll
        for (int n = 0; n < 4; ++n) {
            const int cc = ocol + n * 16;
            if (cc < OCOLS) {
                #pragma unroll
                for (int r = 0; r < 4; ++r) {
                    C[(size_t)(orow + m * 16 + r) * OCOLS + cc] = acc[m][n][r];
                }
            }
        }
    }
}

// ---------------------------------------------------------------------------
extern "C" void kernel_launch(void* const* d_in, const int* in_sizes, int n_in,
                              void* d_out, int out_size, void* d_ws, size_t ws_size,
                              hipStream_t stream)
{
    const float* sk  = (const float*)d_in[0];   // (16,16,125,12)
    const float* ang = (const float*)d_in[1];   // (32000,25)
    const float* W   = (const float*)d_in[2];   // (12,720)
    const float* TP  = (const float*)d_in[3];   // (2704,2704)
    float* out = (float*)d_out;                 // (32000,2704)

    __hip_bfloat16* filt = (__hip_bfloat16*)d_ws;              // N_ROWS*KP bf16
    __hip_bfloat16* Mb   = filt + (size_t)N_ROWS * KP;         // OPAD*KP bf16
    // ws needed: (32000*2720 + 2816*2720)*2 B ~= 181 MiB

    build_filt<<<N_ROWS, 256, 0, stream>>>(sk, ang, W, filt);

    const int totM = OPAD * KP;
    cvt_M<<<(totM + 255) / 256, 256, 0, stream>>>(TP, Mb);

    dim3 grid(OPAD / BN, N_ROWS / BM);  // (22, 250)
    gemm_bt<<<grid, 256, 0, stream>>>(filt, Mb, out);
}

// Round 2
// 540.481 us; speedup vs baseline: 1.6687x; 1.6687x over previous
//
#include <hip/hip_runtime.h>
#include <hip/hip_bf16.h>

// Problem geometry
#define N_ROWS 32000   // Q_OUT*Q_IN*NUM_P
#define SB     12      // SCALAR_BASIS
#define FC     720     // FILTER_C
#define FD     2704    // FILTER_DIM
#define KST    2752    // FD padded to 43*64 (BK=64 tiles)
#define NT     43      // K tiles
#define OCOLS  2704    // DIM_OUT*DIM_IN
#define OPAD   2816    // OCOLS padded to 11*256
#define ANGD   25

typedef __attribute__((ext_vector_type(8))) short bf16x8;
typedef __attribute__((ext_vector_type(4))) float f32x4;

__device__ __forceinline__ void gload16(const void* g, void* l) {
    __builtin_amdgcn_global_load_lds(
        (const __attribute__((address_space(1))) void*)g,
        (__attribute__((address_space(3))) void*)l, 16, 0, 0);
}

// ---------------------------------------------------------------------------
// Kernel 1: per-row n, sc = sk @ (W/sqrt(12)); expand to bf16 filt row (KST)
// ---------------------------------------------------------------------------
__global__ void build_filt(const float* __restrict__ sk,
                           const float* __restrict__ ang,
                           const float* __restrict__ W,
                           __hip_bfloat16* __restrict__ filt)
{
    const int n   = blockIdx.x;
    const int tid = threadIdx.x;  // 256
    __shared__ float s_sc[FC];
    __shared__ float s_ang[ANGD];
    __shared__ float s_sk[SB];

    if (tid < SB) s_sk[tid] = sk[(size_t)n * SB + tid];
    if (tid >= 32 && tid < 32 + ANGD) s_ang[tid - 32] = ang[(size_t)n * ANGD + (tid - 32)];
    __syncthreads();

    const float inv = 0.28867513459481288f; // 1/sqrt(12)
    for (int c = tid; c < FC; c += 256) {
        float acc = 0.f;
        #pragma unroll
        for (int s = 0; s < SB; ++s) acc += s_sk[s] * W[s * FC + c];
        s_sc[c] = acc * inv;
    }
    __syncthreads();

    const size_t base = (size_t)n * KST;
    for (int f = tid; f < KST; f += 256) {
        float v = 0.f;
        if (f < FD) {
            int c, j, a;
            if (f < 144)       { c = f;                         j = 0;            a = 0;  }
            else if (f < 960)  { int t = f - 144;  c = 144 + t/3; j = t - (t/3)*3; a = 1;  }
            else if (f < 2000) { int t = f - 960;  c = 416 + t/5; j = t - (t/5)*5; a = 4;  }
            else if (f < 2560) { int t = f - 2000; c = 624 + t/7; j = t - (t/7)*7; a = 9;  }
            else               { int t = f - 2560; c = 704 + t/9; j = t - (t/9)*9; a = 16; }
            v = s_sc[c] * s_ang[a + j];
        }
        filt[base + f] = __float2bfloat16(v);
    }
}

// ---------------------------------------------------------------------------
// Kernel 2: TP_mixing (2704x2704 f32) -> bf16 padded (OPAD x KST), pad = 0
// ---------------------------------------------------------------------------
__global__ void cvt_M(const float* __restrict__ M, __hip_bfloat16* __restrict__ out)
{
    size_t idx = (size_t)blockIdx.x * 256 + threadIdx.x;
    const size_t total = (size_t)OPAD * KST;
    if (idx >= total) return;
    int o = (int)(idx / KST);
    int k = (int)(idx - (size_t)o * KST);
    float v = (o < OCOLS && k < FD) ? M[(size_t)o * FD + k] : 0.f;
    out[idx] = __float2bfloat16(v);
}

// ---------------------------------------------------------------------------
// Kernel 3: 256x256-tile 8-phase bf16 GEMM (m201 structure).
// C[n,o] = sum_k A[n,k]*B[o,k]. A:(N_ROWS,KST) B:(OPAD,KST) bf16, C f32.
// 8 waves (2M x 4N), per-wave 128x64 out. BK=64, 2 LDS dbuf, XOR swizzle,
// one half-tile staged per phase, counted vmcnt(6), setprio around MFMA.
// ---------------------------------------------------------------------------
__global__ __launch_bounds__(512, 2) void gemm_bt(
    const __hip_bfloat16* __restrict__ A,
    const __hip_bfloat16* __restrict__ B,
    float* __restrict__ C)
{
    __shared__ __align__(1024) char lds[131072];
    char* const ldsA = lds;           // 2 buf x 2 half x 16384 B
    char* const ldsB = lds + 65536;

    const int tid  = threadIdx.x;
    const int wave = tid >> 6;
    const int lane = tid & 63;

    // Bijective XCD swizzle: nwg=1375, q=171, r=7 (m204)
    const int orig = blockIdx.x;
    const int xcd = orig & 7, idx = orig >> 3;
    const int wgid = (xcd < 7 ? xcd * 172 : 1204 + (xcd - 7) * 171) + idx;
    const int bm = wgid / 11;
    const int bn = wgid - bm * 11;
    const size_t arow0 = (size_t)bm * 256;
    const size_t brow0 = (size_t)bn * 256;

    const int wr = wave >> 2;   // 0..1 (M)
    const int wc = wave & 3;    // 0..3 (N)

    // ---- staging lane constants ----
    // One STAGE = 2 x global_load_lds(16B): rnd r covers rows r*64 + wave*8 + (lane>>3),
    // LDS linear dest; global source pre-swizzled: slot = (lane&7) ^ (lane>>3)&7.
    const int lrow  = lane >> 3;
    const int lslot = ((lane & 7) ^ (lrow & 7)) << 4;   // bytes within 128B row

    auto STAGE = [&](const char* gbase, size_t growbase, int tile, char* lbase) {
        const char* g0 = gbase + (growbase + (size_t)(wave * 8 + lrow)) * (KST * 2)
                               + (size_t)tile * 128 + lslot;
        gload16(g0,                           lbase + wave * 1024);
        gload16(g0 + (size_t)64 * (KST * 2), lbase + 8192 + wave * 1024);
    };

    // ---- reader lane constants ----
    const int rl   = lane & 15;
    const int koct = lane >> 4;
    // physical 16B-slot for k-sub ks: s = (ks*4 + koct) ^ (row&7); row&7 == lane&7
    const int sK0 = ((0 * 4 + koct) ^ (lane & 7)) << 4;
    const int sK1 = ((1 * 4 + koct) ^ (lane & 7)) << 4;
    const int arow = wr * 64 + rl;          // + (q&1)*32 + m*16, half = q>>1
    const int brow = (wc & 1) * 64 + rl;    // + n*16, half = wc>>1
    const int bhalf = wc >> 1;

    f32x4 acc[8][4] = {};   // [q*2+m][n]

    // ---- prologue: tile0 {B0,B1,A0,A1}, tile1 {B0,B1,A0} (order matters!) ----
    STAGE((const char*)B, brow0 + 0,   0, ldsB + 0);
    STAGE((const char*)B, brow0 + 128, 0, ldsB + 16384);
    STAGE((const char*)A, arow0 + 0,   0, ldsA + 0);
    STAGE((const char*)A, arow0 + 128, 0, ldsA + 16384);
    STAGE((const char*)B, brow0 + 0,   1, ldsB + 32768);
    STAGE((const char*)B, brow0 + 128, 1, ldsB + 32768 + 16384);
    STAGE((const char*)A, arow0 + 0,   1, ldsA + 32768);
    asm volatile("s_waitcnt vmcnt(6)" ::: "memory");
    __builtin_amdgcn_s_barrier();

    for (int t = 0; t < NT; ++t) {
        char* const aB  = ldsA + (t & 1) * 32768;
        char* const bB  = ldsB + (t & 1) * 32768;
        char* const aBn = ldsA + ((t + 1) & 1) * 32768;

        bf16x8 bfr[4][2];
        #pragma unroll
        for (int q = 0; q < 4; ++q) {
            asm volatile("" ::: "memory");
            __builtin_amdgcn_sched_barrier(0);

            // --- ds-read this phase's register subtile ---
            bf16x8 af[2][2];
            char* ah = aB + (q >> 1) * 16384;
            #pragma unroll
            for (int m = 0; m < 2; ++m) {
                const int r = arow + (q & 1) * 32 + m * 16;
                af[m][0] = *(const bf16x8*)(ah + r * 128 + sK0);
                af[m][1] = *(const bf16x8*)(ah + r * 128 + sK1);
            }
            if (q == 0) {
                char* bh = bB + bhalf * 16384;
                #pragma unroll
                for (int n = 0; n < 4; ++n) {
                    bfr[n][0] = *(const bf16x8*)(bh + (brow + n * 16) * 128 + sK0);
                    bfr[n][1] = *(const bf16x8*)(bh + (brow + n * 16) * 128 + sK1);
                }
            }

            // --- stage one half-tile (schedule: q0:A1(t+1) q1:B0(t+2) q2:B1(t+2) q3:A0(t+2)) ---
            if (q == 0 && t + 1 < NT) STAGE((const char*)A, arow0 + 128, t + 1, aBn + 16384);
            if (q == 1 && t + 2 < NT) STAGE((const char*)B, brow0 + 0,   t + 2, bB + 0);
            if (q == 2 && t + 2 < NT) STAGE((const char*)B, brow0 + 128, t + 2, bB + 16384);
            if (q == 3 && t + 2 < NT) STAGE((const char*)A, arow0 + 0,   t + 2, aB + 0);

            __builtin_amdgcn_s_barrier();
            asm volatile("s_waitcnt lgkmcnt(0)" ::: "memory");
            __builtin_amdgcn_sched_barrier(0);

            __builtin_amdgcn_s_setprio(1);
            #pragma unroll
            for (int ks = 0; ks < 2; ++ks)
                #pragma unroll
                for (int m = 0; m < 2; ++m)
                    #pragma unroll
                    for (int n = 0; n < 4; ++n)
                        acc[q * 2 + m][n] = __builtin_amdgcn_mfma_f32_16x16x32_bf16(
                            af[m][ks], bfr[n][ks], acc[q * 2 + m][n], 0, 0, 0);
            __builtin_amdgcn_s_setprio(0);
            __builtin_amdgcn_sched_barrier(0);

            // counted vmcnt once per K-tile, at phase end (protects tile t+1's reads)
            if (q == 3 && t + 1 < NT) {
                if (t + 1 == NT - 1) asm volatile("s_waitcnt vmcnt(0)" ::: "memory");
                else                 asm volatile("s_waitcnt vmcnt(6)" ::: "memory");
            }
            __builtin_amdgcn_s_barrier();
        }
    }

    // ---- epilogue: C/D layout col=lane&15, row=(lane>>4)*4+r ----
    const int ocol0 = (int)brow0 + wc * 64 + rl;
    const int orow_l = (lane >> 4) << 2;
    #pragma unroll
    for (int q = 0; q < 4; ++q)
        #pragma unroll
        for (int m = 0; m < 2; ++m) {
            const int grow = (int)arow0 + (q >> 1) * 128 + wr * 64 + (q & 1) * 32 + m * 16 + orow_l;
            #pragma unroll
            for (int n = 0; n < 4; ++n) {
                const int gcol = ocol0 + n * 16;
                if (gcol < OCOLS) {
                    #pragma unroll
                    for (int r = 0; r < 4; ++r)
                        C[(size_t)(grow + r) * OCOLS + gcol] = acc[q * 2 + m][n][r];
                }
            }
        }
}

// ---------------------------------------------------------------------------
extern "C" void kernel_launch(void* const* d_in, const int* in_sizes, int n_in,
                              void* d_out, int out_size, void* d_ws, size_t ws_size,
                              hipStream_t stream)
{
    const float* sk  = (const float*)d_in[0];
    const float* ang = (const float*)d_in[1];
    const float* W   = (const float*)d_in[2];
    const float* TP  = (const float*)d_in[3];
    float* out = (float*)d_out;

    __hip_bfloat16* filt = (__hip_bfloat16*)d_ws;           // N_ROWS*KST bf16
    __hip_bfloat16* Mb   = filt + (size_t)N_ROWS * KST;     // OPAD*KST bf16
    // ws needed: (32000*2752 + 2816*2752)*2 B ~= 192 MiB

    build_filt<<<N_ROWS, 256, 0, stream>>>(sk, ang, W, filt);

    const size_t totM = (size_t)OPAD * KST;
    cvt_M<<<(int)((totM + 255) / 256), 256, 0, stream>>>(TP, Mb);

    gemm_bt<<<125 * 11, 512, 0, stream>>>(filt, Mb, out);
}